// Round 1
// baseline (715.368 us; speedup 1.0000x reference)
//
#include <hip/hip_runtime.h>

#define NPTS 2000000
#define KNBR 10

__global__ __launch_bounds__(256) void arap_loss_kernel(
    const float* __restrict__ pc,     // [N,3]
    const float* __restrict__ initp,  // [N,3]
    const int*   __restrict__ idx,    // [N,K] int32
    const float* __restrict__ dist,   // [N,K]
    const float* __restrict__ wgt,    // [N,K]
    float* __restrict__ out)          // [1]
{
    const int i = blockIdx.x * blockDim.x + threadIdx.x;

    float s1 = 0.0f;   // sum |weighted_sq_diff| over this point's K neighbors
    float s2 = 0.0f;   // LDA term for this point

    if (i < NPTS) {
        const float px = pc[3*i+0], py = pc[3*i+1], pz = pc[3*i+2];
        const float bx = initp[3*i+0], by = initp[3*i+1], bz = initp[3*i+2];

        float adx = 0.0f, ady = 0.0f, adz = 0.0f;  // sum_k (pc[j] - initp[j])

        #pragma unroll
        for (int k = 0; k < KNBR; ++k) {
            const int j = idx[i*KNBR + k];
            const float qx = pc[3*j+0], qy = pc[3*j+1], qz = pc[3*j+2];
            const float jx = initp[3*j+0], jy = initp[3*j+1], jz = initp[3*j+2];

            const float dx = px - qx, dy = py - qy, dz = pz - qz;
            const float d2 = dx*dx + dy*dy + dz*dz;
            const float w  = (d2 - dist[i*KNBR + k]) * wgt[i*KNBR + k];
            s1 += fabsf(w);

            adx += qx - jx; ady += qy - jy; adz += qz - jz;
        }

        const float invK = 1.0f / (float)KNBR;
        adx *= invK; ady *= invK; adz *= invK;
        s2 = fabsf(px - (adx + bx)) + fabsf(py - (ady + by)) + fabsf(pz - (adz + bz));
    }

    // pre-scale: loss = sum1/(N*K) + sum2/(N*3)
    float contrib = s1 * (1.0f / ((float)NPTS * (float)KNBR))
                  + s2 * (1.0f / ((float)NPTS * 3.0f));

    // wave-64 butterfly reduce
    #pragma unroll
    for (int off = 32; off > 0; off >>= 1)
        contrib += __shfl_down(contrib, off);

    __shared__ float wsum[4];  // 256 threads / 64 lanes
    const int lane = threadIdx.x & 63;
    const int wid  = threadIdx.x >> 6;
    if (lane == 0) wsum[wid] = contrib;
    __syncthreads();

    if (threadIdx.x == 0) {
        const float t = wsum[0] + wsum[1] + wsum[2] + wsum[3];
        atomicAdd(out, t);
    }
}

extern "C" void kernel_launch(void* const* d_in, const int* in_sizes, int n_in,
                              void* d_out, int out_size, void* d_ws, size_t ws_size,
                              hipStream_t stream) {
    const float* pc    = (const float*)d_in[0];
    const float* initp = (const float*)d_in[1];
    const int*   idx   = (const int*)  d_in[2];
    const float* dist  = (const float*)d_in[3];
    const float* wgt   = (const float*)d_in[4];
    float* out = (float*)d_out;

    // harness poisons d_out once; zero it every call (graph-capture safe)
    hipMemsetAsync(out, 0, sizeof(float), stream);

    const int threads = 256;
    const int blocks  = (NPTS + threads - 1) / threads;
    arap_loss_kernel<<<blocks, threads, 0, stream>>>(pc, initp, idx, dist, wgt, out);
}

// Round 3
// 399.916 us; speedup vs baseline: 1.7888x; 1.7888x over previous
//
#include <hip/hip_runtime.h>

#define NPTS 2000000
#define KNBR 10

typedef int   v2i __attribute__((ext_vector_type(2)));
typedef float v2f __attribute__((ext_vector_type(2)));

// ---------- pack kernel: rec[i] = {px,py,pz,ix, iy,iz,0,0}  (32 B, sector-aligned) ----------
__global__ __launch_bounds__(256) void pack_kernel(const float* __restrict__ pc,
                                                   const float* __restrict__ initp,
                                                   float4* __restrict__ rec) {
    const int i = blockIdx.x * blockDim.x + threadIdx.x;
    if (i >= NPTS) return;
    const float px = pc[3*i+0], py = pc[3*i+1], pz = pc[3*i+2];
    const float jx = initp[3*i+0], jy = initp[3*i+1], jz = initp[3*i+2];
    rec[2*i+0] = make_float4(px, py, pz, jx);
    rec[2*i+1] = make_float4(jy, jz, 0.f, 0.f);
}

// ---------- main kernel: one thread per point ----------
__global__ __launch_bounds__(256) void arap_packed_kernel(
    const float4* __restrict__ rec,   // [2N] packed records
    const int*    __restrict__ idx,   // [N,K]
    const float*  __restrict__ dist,  // [N,K]
    const float*  __restrict__ wgt,   // [N,K]
    float* __restrict__ out)
{
    const int i = blockIdx.x * blockDim.x + threadIdx.x;

    float s1 = 0.0f, s2 = 0.0f;

    if (i < NPTS) {
        const float4 r0 = rec[2*i+0];
        const float4 r1 = rec[2*i+1];
        const float px = r0.x, py = r0.y, pz = r0.z;
        const float bx = r0.w, by = r1.x, bz = r1.y;

        // streamed rows: non-temporal (no reuse — keep them out of L2/LLC)
        int jj[KNBR]; float dd[KNBR], ww[KNBR];
        const v2i* ip = (const v2i*)&idx[(size_t)i * KNBR];
        const v2f* dp = (const v2f*)&dist[(size_t)i * KNBR];
        const v2f* wp = (const v2f*)&wgt[(size_t)i * KNBR];
        #pragma unroll
        for (int t = 0; t < KNBR/2; ++t) {
            v2i v = __builtin_nontemporal_load(&ip[t]);
            v2f d = __builtin_nontemporal_load(&dp[t]);
            v2f w = __builtin_nontemporal_load(&wp[t]);
            jj[2*t] = v.x; jj[2*t+1] = v.y;
            dd[2*t] = d.x; dd[2*t+1] = d.y;
            ww[2*t] = w.x; ww[2*t+1] = w.y;
        }

        float adx = 0.0f, ady = 0.0f, adz = 0.0f;

        #pragma unroll
        for (int k = 0; k < KNBR; ++k) {
            const int j = jj[k];
            const float4 q0 = rec[2*j+0];   // px,py,pz,ix
            const float4 q1 = rec[2*j+1];   // iy,iz,-,-

            const float dx = px - q0.x, dy = py - q0.y, dz = pz - q0.z;
            const float d2 = dx*dx + dy*dy + dz*dz;
            s1 += fabsf((d2 - dd[k]) * ww[k]);

            adx += q0.x - q0.w;
            ady += q0.y - q1.x;
            adz += q0.z - q1.y;
        }

        const float invK = 1.0f / (float)KNBR;
        adx *= invK; ady *= invK; adz *= invK;
        s2 = fabsf(px - (adx + bx)) + fabsf(py - (ady + by)) + fabsf(pz - (adz + bz));
    }

    float contrib = s1 * (1.0f / ((float)NPTS * (float)KNBR))
                  + s2 * (1.0f / ((float)NPTS * 3.0f));

    #pragma unroll
    for (int off = 32; off > 0; off >>= 1)
        contrib += __shfl_down(contrib, off);

    __shared__ float wsum[4];
    const int lane = threadIdx.x & 63;
    const int wid  = threadIdx.x >> 6;
    if (lane == 0) wsum[wid] = contrib;
    __syncthreads();

    if (threadIdx.x == 0) {
        atomicAdd(out, wsum[0] + wsum[1] + wsum[2] + wsum[3]);
    }
}

// ---------- fallback (ws too small): round-1 kernel ----------
__global__ __launch_bounds__(256) void arap_loss_kernel(
    const float* __restrict__ pc, const float* __restrict__ initp,
    const int* __restrict__ idx, const float* __restrict__ dist,
    const float* __restrict__ wgt, float* __restrict__ out)
{
    const int i = blockIdx.x * blockDim.x + threadIdx.x;
    float s1 = 0.0f, s2 = 0.0f;
    if (i < NPTS) {
        const float px = pc[3*i+0], py = pc[3*i+1], pz = pc[3*i+2];
        const float bx = initp[3*i+0], by = initp[3*i+1], bz = initp[3*i+2];
        float adx = 0.f, ady = 0.f, adz = 0.f;
        #pragma unroll
        for (int k = 0; k < KNBR; ++k) {
            const int j = idx[i*KNBR + k];
            const float qx = pc[3*j+0], qy = pc[3*j+1], qz = pc[3*j+2];
            const float jx = initp[3*j+0], jy = initp[3*j+1], jz = initp[3*j+2];
            const float dx = px - qx, dy = py - qy, dz = pz - qz;
            const float d2 = dx*dx + dy*dy + dz*dz;
            s1 += fabsf((d2 - dist[i*KNBR + k]) * wgt[i*KNBR + k]);
            adx += qx - jx; ady += qy - jy; adz += qz - jz;
        }
        const float invK = 1.0f / (float)KNBR;
        adx *= invK; ady *= invK; adz *= invK;
        s2 = fabsf(px - (adx + bx)) + fabsf(py - (ady + by)) + fabsf(pz - (adz + bz));
    }
    float contrib = s1 * (1.0f / ((float)NPTS * (float)KNBR))
                  + s2 * (1.0f / ((float)NPTS * 3.0f));
    #pragma unroll
    for (int off = 32; off > 0; off >>= 1) contrib += __shfl_down(contrib, off);
    __shared__ float wsum[4];
    const int lane = threadIdx.x & 63, wid = threadIdx.x >> 6;
    if (lane == 0) wsum[wid] = contrib;
    __syncthreads();
    if (threadIdx.x == 0) atomicAdd(out, wsum[0] + wsum[1] + wsum[2] + wsum[3]);
}

extern "C" void kernel_launch(void* const* d_in, const int* in_sizes, int n_in,
                              void* d_out, int out_size, void* d_ws, size_t ws_size,
                              hipStream_t stream) {
    const float* pc    = (const float*)d_in[0];
    const float* initp = (const float*)d_in[1];
    const int*   idx   = (const int*)  d_in[2];
    const float* dist  = (const float*)d_in[3];
    const float* wgt   = (const float*)d_in[4];
    float* out = (float*)d_out;

    (void)hipMemsetAsync(out, 0, sizeof(float), stream);

    const int threads = 256;
    const int blocks  = (NPTS + threads - 1) / threads;

    const size_t need = (size_t)NPTS * 8 * sizeof(float);  // 64 MB
    if (ws_size >= need) {
        float4* rec = (float4*)d_ws;
        pack_kernel<<<blocks, threads, 0, stream>>>(pc, initp, rec);
        arap_packed_kernel<<<blocks, threads, 0, stream>>>(rec, idx, dist, wgt, out);
    } else {
        arap_loss_kernel<<<blocks, threads, 0, stream>>>(pc, initp, idx, dist, wgt, out);
    }
}